// Round 1
// 116.701 us; speedup vs baseline: 1.0911x; 1.0911x over previous
//
#include <hip/hip_runtime.h>
#include <math.h>

#define NB 24
#define DM 128
#define NH 8
#define DK 16
#define LL 512
#define HB (NH * NB)   // 192

// ---------------------------------------------------------------------------
// Workspace layout (BYTES), ~31 MB total:
//   xThi/xTlo [NB][LL][DM] ushort : x transposed, split bf16 (B-frag layout)
//   Whi/Wlo   [HB][3][16][128]    : W split bf16 (A-frag layout), idx hb*3+mat
//   Wob       [NB][128][128]      : Wo plain bf16
//   qb/kb     [HB][LL][32]        : split rows, [0:16]=hi(k) [16:32]=lo(k);
//                                   K pre-scaled by 0.25*log2e
//   vb        [HB][DK][LL]        : V plain bf16
//   headT     [NB][LL][DM]        : attention out, bf16, B-frag layout for Wo
// ---------------------------------------------------------------------------
#define XTH_OFF 0
#define XTL_OFF 3145728
#define WHI_OFF 6291456
#define WLO_OFF 8650752
#define WOB_OFF 11010048
#define QB_OFF  11796480
#define KB_OFF  18087936
#define VB_OFF  24379392
#define HT_OFF  27525120

typedef __attribute__((ext_vector_type(8))) short bf16x8;   // 4 VGPR MFMA A/B
typedef __attribute__((ext_vector_type(4))) float f32x4;    // MFMA C/D
typedef __attribute__((ext_vector_type(4))) int   i32x4;

#define MFMA  __builtin_amdgcn_mfma_f32_16x16x32_bf16
#define EXP2  __builtin_amdgcn_exp2f
#define BPERM __builtin_amdgcn_ds_bpermute

// bf16 rounding (round-half-up), result kept in the high half of a uint
static __device__ __forceinline__ unsigned bfr(float x) {
    return (__float_as_uint(x) + 0x8000u) & 0xffff0000u;
}

// packed bf16 pair via HW cvt: lo16 = bf16(a), hi16 = bf16(b)  (RNE)
static __device__ __forceinline__ unsigned cvtpk(float a, float b) {
    unsigned r;
    asm("v_cvt_pk_bf16_f32 %0, %1, %2" : "=v"(r) : "v"(a), "v"(b));
    return r;
}

// ---------------------------------------------------------------------------
// Kernel 0: prep. 864 blocks:
//   [0,192)   x -> xThi/xTlo  (LDS transpose in TWO 64-row halves so static
//             LDS is 16.6 KB, not 133 KB -> 8 blocks/CU instead of 1)
//   [192,768) W split, w=bid-192: hb=w/3 mat=w%3
//   [768,864) Wo -> bf16
// All bf16 stores packed 2-per-lane (4 B/lane).
// ---------------------------------------------------------------------------
__global__ __launch_bounds__(256)
void prep(const float* __restrict__ x,
          const float* __restrict__ Wq,
          const float* __restrict__ Wk,
          const float* __restrict__ Wv,
          const float* __restrict__ Wo,
          unsigned short* __restrict__ xthi,
          unsigned short* __restrict__ xtlo,
          unsigned short* __restrict__ whi,
          unsigned short* __restrict__ wlo,
          unsigned short* __restrict__ wob)
{
    __shared__ float T[64][65];                       // 16.6 KB
    const int bid = blockIdx.x, tid = threadIdx.x;

    if (bid < 192) {
        const int b = bid >> 3, lc = bid & 7;
        #pragma unroll
        for (int half = 0; half < 2; ++half) {
            const int d0 = half << 6;
            const float* __restrict__ xb =
                x + (size_t)b * 65536 + (size_t)d0 * LL + lc * 64;
            if (half) __syncthreads();                // T reuse fence
            #pragma unroll
            for (int i = 0; i < 16; ++i) {            // coalesced 64-float runs
                const int idx = i * 256 + tid;
                T[idx >> 6][idx & 63] = xb[(size_t)(idx >> 6) * LL + (idx & 63)];
            }
            __syncthreads();
            #pragma unroll
            for (int i = 0; i < 8; ++i) {             // 2 elems/lane, packed
                const int idx = (i * 256 + tid) * 2;
                const int l = idx >> 6, dd = idx & 63;
                const float v0 = T[dd][l], v1 = T[dd + 1][l];
                const unsigned h0 = bfr(v0), h1 = bfr(v1);
                const unsigned e0 = bfr(v0 - __uint_as_float(h0));
                const unsigned e1 = bfr(v1 - __uint_as_float(h1));
                const size_t o = (size_t)b * 65536 +
                                 (size_t)(lc * 64 + l) * DM + d0 + dd;
                *(unsigned*)(xthi + o) = (h0 >> 16) | (h1 & 0xffff0000u);
                *(unsigned*)(xtlo + o) = (e0 >> 16) | (e1 & 0xffff0000u);
            }
        }
    } else if (bid < 768) {
        const int w = bid - 192, hb = w / 3, mat = w - hb * 3;
        const float* __restrict__ src =
            (mat == 0 ? Wq : (mat == 1 ? Wk : Wv)) + (size_t)hb * 2048;
        unsigned short* __restrict__ dh = whi + (size_t)w * 2048;
        unsigned short* __restrict__ dl = wlo + (size_t)w * 2048;
        for (int i = tid; i < 1024; i += 256) {
            const float v0 = src[2 * i], v1 = src[2 * i + 1];
            const unsigned h0 = bfr(v0), h1 = bfr(v1);
            const unsigned e0 = bfr(v0 - __uint_as_float(h0));
            const unsigned e1 = bfr(v1 - __uint_as_float(h1));
            *(unsigned*)(dh + 2 * i) = (h0 >> 16) | (h1 & 0xffff0000u);
            *(unsigned*)(dl + 2 * i) = (e0 >> 16) | (e1 & 0xffff0000u);
        }
    } else {
        const int w = bid - 768;                      // 96 blocks x 4096
        const float* __restrict__ src = Wo + (size_t)w * 4096;
        unsigned short* __restrict__ d = wob + (size_t)w * 4096;
        for (int i = tid; i < 2048; i += 256) {
            const float v0 = src[2 * i], v1 = src[2 * i + 1];
            *(unsigned*)(d + 2 * i) = (bfr(v0) >> 16) | (bfr(v1) & 0xffff0000u);
        }
    }
}

// ---------------------------------------------------------------------------
// Kernel 1: QKV projection on MFMA. 768 blocks = (hb, nc 4) x 4 waves;
// wave = 2 n-tiles (32 l) x ALL THREE mats -> each x B-fragment feeds 18
// MFMAs instead of 6 (x L2 traffic /3). W A-frags are L1-resident (12 KB/hb).
// Split product (Whi+Wlo)(xhi+xlo) via 3 MFMAs (lo*lo ~2^-16 rel, dropped).
// C emitted straight into the attention layouts.
// ---------------------------------------------------------------------------
__global__ __launch_bounds__(256)
void qkv_mfma(const unsigned short* __restrict__ xthi,
              const unsigned short* __restrict__ xtlo,
              const unsigned short* __restrict__ whi,
              const unsigned short* __restrict__ wlo,
              unsigned short* __restrict__ qb,
              unsigned short* __restrict__ kb,
              unsigned short* __restrict__ vb)
{
    const int blk  = blockIdx.x;
    const int nc   = blk & 3;         // 128-l chunk
    const int hb   = blk >> 2;
    const int b    = hb % NB;
    const int wv   = threadIdx.x >> 6;
    const int lane = threadIdx.x & 63;
    const int g = lane >> 4, mR = lane & 15;
    const int l0 = nc * 128 + wv * 32;

    const unsigned short* __restrict__ wAh =
        whi + (size_t)hb * 6144 + mR * 128 + g * 8;
    const unsigned short* __restrict__ wAl =
        wlo + (size_t)hb * 6144 + mR * 128 + g * 8;
    const unsigned short* __restrict__ xh = xthi + (size_t)b * 65536 + g * 8;
    const unsigned short* __restrict__ xl = xtlo + (size_t)b * 65536 + g * 8;

    f32x4 C[3][2];
    #pragma unroll
    for (int m = 0; m < 3; ++m)
        #pragma unroll
        for (int t = 0; t < 2; ++t) C[m][t] = (f32x4){0.f, 0.f, 0.f, 0.f};

    #pragma unroll
    for (int kk = 0; kk < 4; ++kk) {
        bf16x8 bH[2], bL[2];
        #pragma unroll
        for (int t = 0; t < 2; ++t) {
            const size_t lo_ = (size_t)(l0 + t * 16 + mR) * DM + kk * 32;
            bH[t] = *(const bf16x8*)(xh + lo_);
            bL[t] = *(const bf16x8*)(xl + lo_);
        }
        #pragma unroll
        for (int m = 0; m < 3; ++m) {
            const bf16x8 aH = *(const bf16x8*)(wAh + m * 2048 + kk * 32);
            const bf16x8 aL = *(const bf16x8*)(wAl + m * 2048 + kk * 32);
            #pragma unroll
            for (int t = 0; t < 2; ++t) {
                C[m][t] = MFMA(aH, bH[t], C[m][t], 0, 0, 0);
                C[m][t] = MFMA(aH, bL[t], C[m][t], 0, 0, 0);
                C[m][t] = MFMA(aL, bH[t], C[m][t], 0, 0, 0);
            }
        }
    }

    {                                                 // V -> [hb][v][l] bf16
        unsigned short* __restrict__ vo = vb + (size_t)hb * 8192;
        #pragma unroll
        for (int t = 0; t < 2; ++t) {
            const int l = l0 + t * 16 + mR;
            #pragma unroll
            for (int i = 0; i < 4; ++i)
                vo[(size_t)(4 * g + i) * LL + l] =
                    (unsigned short)(bfr(C[2][t][i]) >> 16);
        }
    }
    #pragma unroll
    for (int m = 0; m < 2; ++m) {                     // Q/K -> split rows
        const float scale = m ? (0.25f * 1.44269504f) : 1.0f;
        unsigned short* __restrict__ dst =
            (m ? kb : qb) + (size_t)hb * LL * 32;
        #pragma unroll
        for (int t = 0; t < 2; ++t) {
            const int l = l0 + t * 16 + mR;
            ushort4 hi4, lo4;
            #pragma unroll
            for (int i = 0; i < 4; ++i) {
                const float v = C[m][t][i] * scale;
                const unsigned h = bfr(v);
                const unsigned lw = bfr(v - __uint_as_float(h));
                ((unsigned short*)&hi4)[i] = (unsigned short)(h >> 16);
                ((unsigned short*)&lo4)[i] = (unsigned short)(lw >> 16);
            }
            *(ushort4*)(dst + (size_t)l * 32 + 4 * g)      = hi4;
            *(ushort4*)(dst + (size_t)l * 32 + 16 + 4 * g) = lo4;
        }
    }
}

// ---------------------------------------------------------------------------
// Kernel 2: MFMA flash attention (softmax over l = query axis). Changes vs
// validated round-9 body: (a) bf16 pack of P via v_cvt_pk_bf16_f32 (4 instrs
// instead of 8 bfr + 4 pk2; denominator still sums the exact packed bf16
// values, now RNE-rounded), (b) column-group guards split so a tile
// triggering only one group does half the softmax work.
// ---------------------------------------------------------------------------
static __device__ __forceinline__ void soft_pv(
    const f32x4& s0, const f32x4& s1, float tm, float& bar, float& sm,
    f32x4& O, const bf16x8& aV, int aLo, int aHi, bool up)
{
    const float nb = fmaxf(bar, tm + 32.f);
    const float f  = EXP2(bar - nb);
    bar = nb;
    const unsigned c0 = cvtpk(EXP2(s0[0] - nb), EXP2(s0[1] - nb));
    const unsigned c1 = cvtpk(EXP2(s0[2] - nb), EXP2(s0[3] - nb));
    const unsigned c2 = cvtpk(EXP2(s1[0] - nb), EXP2(s1[1] - nb));
    const unsigned c3 = cvtpk(EXP2(s1[2] - nb), EXP2(s1[3] - nb));
    const float sacc =
        ((__uint_as_float(c0 << 16) + __uint_as_float(c0 & 0xffff0000u)) +
         (__uint_as_float(c1 << 16) + __uint_as_float(c1 & 0xffff0000u))) +
        ((__uint_as_float(c2 << 16) + __uint_as_float(c2 & 0xffff0000u)) +
         (__uint_as_float(c3 << 16) + __uint_as_float(c3 & 0xffff0000u)));
    sm = fmaf(sm, f, sacc);
    O *= f;
    const int p00 = BPERM(aLo, (int)c0), p02 = BPERM(aLo, (int)c2);
    const int p10 = BPERM(aLo, (int)c1), p12 = BPERM(aLo, (int)c3);
    const int p20 = BPERM(aHi, (int)c0), p22 = BPERM(aHi, (int)c2);
    const int p30 = BPERM(aHi, (int)c1), p32 = BPERM(aHi, (int)c3);
    i32x4 bi = { up ? p00 : p02, up ? p10 : p12,
                 up ? p20 : p22, up ? p30 : p32 };
    O = MFMA(aV, __builtin_bit_cast(bf16x8, bi), O, 0, 0, 0);
}

__global__ __launch_bounds__(256)
void attn_mfma(const unsigned short* __restrict__ qb,
               const unsigned short* __restrict__ kb,
               const unsigned short* __restrict__ vb,
               unsigned short* __restrict__ ht)
{
    const int hb   = blockIdx.x >> 2;
    const int mc   = blockIdx.x & 3;
    const int tid  = threadIdx.x;
    const int wave = tid >> 6;
    const int lane = tid & 63;
    const int g    = lane >> 4;
    const int mR   = lane & 15;
    const int mb   = mc * 128 + wave * 32;

    const unsigned short* Kr0 = kb + ((size_t)hb * LL + mb + mR) * 32;
    const unsigned short* Kr1 = Kr0 + 16 * 32;
    const bf16x8 bK0  = *(const bf16x8*)(Kr0 + g * 8);
    const bf16x8 bK0s = *(const bf16x8*)(Kr0 + (g ^ 2) * 8);
    const bf16x8 bK1  = *(const bf16x8*)(Kr1 + g * 8);
    const bf16x8 bK1s = *(const bf16x8*)(Kr1 + (g ^ 2) * 8);

    const unsigned short* qrow = qb + ((size_t)hb * LL + mR) * 32 + g * 8;
    const unsigned short* vrow = vb + ((size_t)hb * DK + mR) * LL + g * 8;

    f32x4 O0 = {0.f,0.f,0.f,0.f}, O1 = {0.f,0.f,0.f,0.f};
    float bar0 = -1e30f, bar1 = -1e30f, sm0 = 0.f, sm1 = 0.f;

    const int aLo = ((g & 1) * 32 + mR) * 4;
    const int aHi = aLo + 64;
    const bool up = (g < 2);

    for (int l = 0; l < LL; l += 32) {
        const bf16x8 aQ0 = *(const bf16x8*)(qrow + (size_t)l * 32);
        const bf16x8 aQ1 = *(const bf16x8*)(qrow + (size_t)(l + 16) * 32);

        const f32x4 z = {0.f,0.f,0.f,0.f};
        f32x4 sA0 = MFMA(aQ0, bK0, z, 0,0,0);  sA0 = MFMA(aQ0, bK0s, sA0, 0,0,0);
        f32x4 sB0 = MFMA(aQ0, bK1, z, 0,0,0);  sB0 = MFMA(aQ0, bK1s, sB0, 0,0,0);
        f32x4 sA1 = MFMA(aQ1, bK0, z, 0,0,0);  sA1 = MFMA(aQ1, bK0s, sA1, 0,0,0);
        f32x4 sB1 = MFMA(aQ1, bK1, z, 0,0,0);  sB1 = MFMA(aQ1, bK1s, sB1, 0,0,0);

        float tmA = fmaxf(fmaxf(fmaxf(sA0[0],sA0[1]), fmaxf(sA0[2],sA0[3])),
                          fmaxf(fmaxf(sA1[0],sA1[1]), fmaxf(sA1[2],sA1[3])));
        float tmB = fmaxf(fmaxf(fmaxf(sB0[0],sB0[1]), fmaxf(sB0[2],sB0[3])),
                          fmaxf(fmaxf(sB1[0],sB1[1]), fmaxf(sB1[2],sB1[3])));
        tmA = fmaxf(tmA, __shfl_xor(tmA, 16, 64));
        tmA = fmaxf(tmA, __shfl_xor(tmA, 32, 64));
        tmB = fmaxf(tmB, __shfl_xor(tmB, 16, 64));
        tmB = fmaxf(tmB, __shfl_xor(tmB, 32, 64));

        const bool pA = __any(tmA + 64.f > bar0);
        const bool pB = __any(tmB + 64.f > bar1);
        if (pA || pB) {
            const bf16x8 aV = *(const bf16x8*)(vrow + l);
            if (pA) soft_pv(sA0, sA1, tmA, bar0, sm0, O0, aV, aLo, aHi, up);
            if (pB) soft_pv(sB0, sB1, tmB, bar1, sm1, O1, aV, aLo, aHi, up);
        }
    }

    sm0 += __shfl_xor(sm0, 16, 64);  sm0 += __shfl_xor(sm0, 32, 64);
    sm1 += __shfl_xor(sm1, 16, 64);  sm1 += __shfl_xor(sm1, 32, 64);
    const float i0 = 1.f / sm0, i1 = 1.f / sm1;

    const int h = hb / NB, bb = hb % NB;
    // headT[b][l][d]: lane writes d = h*16+4g..+3 at l = mb+mR (and +16)
    unsigned short* __restrict__ ho =
        ht + (size_t)bb * 65536 + (size_t)(mb + mR) * DM + h * 16 + 4 * g;
    ushort4 p0, p1;
    #pragma unroll
    for (int i = 0; i < 4; ++i) {
        ((unsigned short*)&p0)[i] = (unsigned short)(bfr(O0[i] * i0) >> 16);
        ((unsigned short*)&p1)[i] = (unsigned short)(bfr(O1[i] * i1) >> 16);
    }
    *(ushort4*)ho              = p0;
    *(ushort4*)(ho + 16 * DM)  = p1;
}

// ---------------------------------------------------------------------------
// Kernel 3: out = Wo @ headT on MFMA. 768 blocks = (b, mq 2, nq 16) x 4 waves;
// wave = m-tile (mq*4+w), 2 n-tiles. Per kstep: 1 A + 2 B loads + 2 MFMA.
// ---------------------------------------------------------------------------
__global__ __launch_bounds__(256)
void out_mfma(const unsigned short* __restrict__ wob,
              const unsigned short* __restrict__ ht,
              float* __restrict__ out)
{
    const int blk  = blockIdx.x;
    const int b    = blk >> 5;
    const int mq   = (blk >> 4) & 1;
    const int nq   = blk & 15;
    const int wv   = threadIdx.x >> 6;
    const int lane = threadIdx.x & 63;
    const int g = lane >> 4, mR = lane & 15;
    const int m0 = (mq * 4 + wv) * 16;
    const int n0 = nq * 32;

    const unsigned short* __restrict__ A =
        wob + (size_t)b * 16384 + (size_t)(m0 + mR) * DM + g * 8;
    const unsigned short* __restrict__ B = ht + (size_t)b * 65536 + g * 8;

    f32x4 C0 = {0.f,0.f,0.f,0.f}, C1 = {0.f,0.f,0.f,0.f};
    #pragma unroll
    for (int kk = 0; kk < 4; ++kk) {
        const bf16x8 aW = *(const bf16x8*)(A + kk * 32);
        const bf16x8 b0 = *(const bf16x8*)(B + (size_t)(n0 + mR) * DM + kk * 32);
        const bf16x8 b1 = *(const bf16x8*)(B + (size_t)(n0 + 16 + mR) * DM + kk * 32);
        C0 = MFMA(aW, b0, C0, 0, 0, 0);
        C1 = MFMA(aW, b1, C1, 0, 0, 0);
    }

    float* __restrict__ ob = out + (size_t)b * 65536 + (size_t)(m0 + 4 * g) * LL;
    #pragma unroll
    for (int i = 0; i < 4; ++i) {
        ob[(size_t)i * LL + n0 + mR]      = C0[i];
        ob[(size_t)i * LL + n0 + 16 + mR] = C1[i];
    }
}

extern "C" void kernel_launch(void* const* d_in, const int* in_sizes, int n_in,
                              void* d_out, int out_size, void* d_ws, size_t ws_size,
                              hipStream_t stream) {
    const float* x  = (const float*)d_in[0];
    const float* Wq = (const float*)d_in[1];
    const float* Wk = (const float*)d_in[2];
    const float* Wv = (const float*)d_in[3];
    const float* Wo = (const float*)d_in[4];
    float* out = (float*)d_out;

    char* ws = (char*)d_ws;
    unsigned short* xthi = (unsigned short*)(ws + XTH_OFF);
    unsigned short* xtlo = (unsigned short*)(ws + XTL_OFF);
    unsigned short* whi  = (unsigned short*)(ws + WHI_OFF);
    unsigned short* wlo  = (unsigned short*)(ws + WLO_OFF);
    unsigned short* wob  = (unsigned short*)(ws + WOB_OFF);
    unsigned short* qb   = (unsigned short*)(ws + QB_OFF);
    unsigned short* kb   = (unsigned short*)(ws + KB_OFF);
    unsigned short* vb   = (unsigned short*)(ws + VB_OFF);
    unsigned short* ht   = (unsigned short*)(ws + HT_OFF);

    prep     <<<864,     256, 0, stream>>>(x, Wq, Wk, Wv, Wo, xthi, xtlo, whi, wlo, wob);
    qkv_mfma <<<HB * 4,  256, 0, stream>>>(xthi, xtlo, whi, wlo, qb, kb, vb);
    attn_mfma<<<HB * 4,  256, 0, stream>>>(qb, kb, vb, ht);
    out_mfma <<<NB * 32, 256, 0, stream>>>(wob, ht, out);
}

// Round 2
// 115.203 us; speedup vs baseline: 1.1053x; 1.0130x over previous
//
#include <hip/hip_runtime.h>
#include <math.h>

#define NB 24
#define DM 128
#define NH 8
#define DK 16
#define LL 512
#define HB (NH * NB)   // 192

// ---------------------------------------------------------------------------
// Workspace layout (BYTES):
//   xThi/xTlo [NB][LL][DM] ushort : x transposed, split bf16 (B-frag layout)
//   Whi/Wlo   [HB][3][16][128]    : W split bf16 (A-frag layout), idx hb*3+mat
//   headT     [NB][LL][DM]        : attention out, bf16, B-frag layout for Wo
// (qb/kb/vb are now LDS-resident inside the fused kernel; wob dropped --
//  out_mfma converts fp32 Wo on the fly.)
// ---------------------------------------------------------------------------
#define XTH_OFF 0
#define XTL_OFF 3145728
#define WHI_OFF 6291456
#define WLO_OFF 8650752
#define HT_OFF  11010048

typedef __attribute__((ext_vector_type(8))) short bf16x8;   // 4 VGPR MFMA A/B
typedef __attribute__((ext_vector_type(4))) float f32x4;    // MFMA C/D
typedef __attribute__((ext_vector_type(4))) int   i32x4;

#define MFMA  __builtin_amdgcn_mfma_f32_16x16x32_bf16
#define EXP2  __builtin_amdgcn_exp2f
#define BPERM __builtin_amdgcn_ds_bpermute

// bf16 rounding (round-half-up), result kept in the high half of a uint
static __device__ __forceinline__ unsigned bfr(float x) {
    return (__float_as_uint(x) + 0x8000u) & 0xffff0000u;
}

// packed bf16 pair via HW cvt: lo16 = bf16(a), hi16 = bf16(b)  (RNE)
static __device__ __forceinline__ unsigned cvtpk(float a, float b) {
    unsigned r;
    asm("v_cvt_pk_bf16_f32 %0, %1, %2" : "=v"(r) : "v"(a), "v"(b));
    return r;
}

// ---------------------------------------------------------------------------
// Kernel 0: prep. 768 blocks:
//   [0,192)   x -> xThi/xTlo  (LDS transpose, two 64-row halves, 16.6 KB LDS)
//   [192,768) W split, w=bid-192: hb=w/3 mat=w%3
// ---------------------------------------------------------------------------
__global__ __launch_bounds__(256)
void prep(const float* __restrict__ x,
          const float* __restrict__ Wq,
          const float* __restrict__ Wk,
          const float* __restrict__ Wv,
          unsigned short* __restrict__ xthi,
          unsigned short* __restrict__ xtlo,
          unsigned short* __restrict__ whi,
          unsigned short* __restrict__ wlo)
{
    __shared__ float T[64][65];                       // 16.6 KB
    const int bid = blockIdx.x, tid = threadIdx.x;

    if (bid < 192) {
        const int b = bid >> 3, lc = bid & 7;
        #pragma unroll
        for (int half = 0; half < 2; ++half) {
            const int d0 = half << 6;
            const float* __restrict__ xb =
                x + (size_t)b * 65536 + (size_t)d0 * LL + lc * 64;
            if (half) __syncthreads();                // T reuse fence
            #pragma unroll
            for (int i = 0; i < 16; ++i) {            // coalesced 64-float runs
                const int idx = i * 256 + tid;
                T[idx >> 6][idx & 63] = xb[(size_t)(idx >> 6) * LL + (idx & 63)];
            }
            __syncthreads();
            #pragma unroll
            for (int i = 0; i < 8; ++i) {             // 2 elems/lane, packed
                const int idx = (i * 256 + tid) * 2;
                const int l = idx >> 6, dd = idx & 63;
                const float v0 = T[dd][l], v1 = T[dd + 1][l];
                const unsigned h0 = bfr(v0), h1 = bfr(v1);
                const unsigned e0 = bfr(v0 - __uint_as_float(h0));
                const unsigned e1 = bfr(v1 - __uint_as_float(h1));
                const size_t o = (size_t)b * 65536 +
                                 (size_t)(lc * 64 + l) * DM + d0 + dd;
                *(unsigned*)(xthi + o) = (h0 >> 16) | (h1 & 0xffff0000u);
                *(unsigned*)(xtlo + o) = (e0 >> 16) | (e1 & 0xffff0000u);
            }
        }
    } else {
        const int w = bid - 192, hb = w / 3, mat = w - hb * 3;
        const float* __restrict__ src =
            (mat == 0 ? Wq : (mat == 1 ? Wk : Wv)) + (size_t)hb * 2048;
        unsigned short* __restrict__ dh = whi + (size_t)w * 2048;
        unsigned short* __restrict__ dl = wlo + (size_t)w * 2048;
        for (int i = tid; i < 1024; i += 256) {
            const float v0 = src[2 * i], v1 = src[2 * i + 1];
            const unsigned h0 = bfr(v0), h1 = bfr(v1);
            const unsigned e0 = bfr(v0 - __uint_as_float(h0));
            const unsigned e1 = bfr(v1 - __uint_as_float(h1));
            *(unsigned*)(dh + 2 * i) = (h0 >> 16) | (h1 & 0xffff0000u);
            *(unsigned*)(dl + 2 * i) = (e0 >> 16) | (e1 & 0xffff0000u);
        }
    }
}

// ---------------------------------------------------------------------------
// Fused QKV + attention. 192 blocks (one per hb) x 512 threads (8 waves).
// Phase 1: wave wv computes Q/K/V for l in [wv*64, wv*64+64) -- identical
//   MFMA structure to the validated qkv kernel -- and stores into LDS with
//   the validated qb/kb/vb layouts, strides padded 32->40 / 512->520 ushorts
//   so all phase-2 ds_read_b128 are bank-conflict-free
//   (quads: Q/K (5*mR+g)&7, V (mR+g+4j)&7 -- uniform 8 lanes/quad).
// Phase 2: wave wv runs the validated online-softmax attention for
//   m in [wv*64, wv*64+64) (2 sub-tiles; K frags preloaded once; Q/V LDS
//   loads shared across sub-tiles). Softmax denominator now sums the raw
//   f32 exp2 values (pre-pack): ~0.4% denominator/numerator mismatch worst
//   case, well under budget.
// Saves the 31 MB qb/kb/vb HBM round-trip + one launch drain.
// ---------------------------------------------------------------------------
static __device__ __forceinline__ void soft_pv(
    const f32x4& s0, const f32x4& s1, float tm, float& bar, float& sm,
    f32x4& O, const bf16x8& aV, int aLo, int aHi, bool up)
{
    const float nb = fmaxf(bar, tm + 32.f);
    const float f  = EXP2(bar - nb);
    bar = nb;
    const float e0 = EXP2(s0[0] - nb), e1 = EXP2(s0[1] - nb);
    const float e2 = EXP2(s0[2] - nb), e3 = EXP2(s0[3] - nb);
    const float e4 = EXP2(s1[0] - nb), e5 = EXP2(s1[1] - nb);
    const float e6 = EXP2(s1[2] - nb), e7 = EXP2(s1[3] - nb);
    const float sacc = ((e0 + e1) + (e2 + e3)) + ((e4 + e5) + (e6 + e7));
    sm = fmaf(sm, f, sacc);
    O *= f;
    const unsigned c0 = cvtpk(e0, e1), c1 = cvtpk(e2, e3);
    const unsigned c2 = cvtpk(e4, e5), c3 = cvtpk(e6, e7);
    const int p00 = BPERM(aLo, (int)c0), p02 = BPERM(aLo, (int)c2);
    const int p10 = BPERM(aLo, (int)c1), p12 = BPERM(aLo, (int)c3);
    const int p20 = BPERM(aHi, (int)c0), p22 = BPERM(aHi, (int)c2);
    const int p30 = BPERM(aHi, (int)c1), p32 = BPERM(aHi, (int)c3);
    i32x4 bi = { up ? p00 : p02, up ? p10 : p12,
                 up ? p20 : p22, up ? p30 : p32 };
    O = MFMA(aV, __builtin_bit_cast(bf16x8, bi), O, 0, 0, 0);
}

#define QK_STRIDE 40     // ushorts per row (32 data + 8 pad)
#define V_STRIDE  520    // ushorts per row (512 data + 8 pad)

__global__ __launch_bounds__(512)
void qkv_attn(const unsigned short* __restrict__ xthi,
              const unsigned short* __restrict__ xtlo,
              const unsigned short* __restrict__ whi,
              const unsigned short* __restrict__ wlo,
              unsigned short* __restrict__ ht)
{
    __shared__ unsigned short qs[LL * QK_STRIDE];    // 40 KB
    __shared__ unsigned short ks[LL * QK_STRIDE];    // 40 KB
    __shared__ unsigned short vs[DK * V_STRIDE];     // 16.25 KB

    const int hb   = blockIdx.x;
    const int b    = hb % NB;
    const int wv   = threadIdx.x >> 6;               // 0..7
    const int lane = threadIdx.x & 63;
    const int g    = lane >> 4;
    const int mR   = lane & 15;
    const int l0   = wv * 64;

    // ---------------- Phase 1: QKV projection into LDS ----------------
    {
        const unsigned short* __restrict__ wAh =
            whi + (size_t)hb * 6144 + mR * 128 + g * 8;
        const unsigned short* __restrict__ wAl =
            wlo + (size_t)hb * 6144 + mR * 128 + g * 8;
        const unsigned short* __restrict__ xh = xthi + (size_t)b * 65536 + g * 8;
        const unsigned short* __restrict__ xl = xtlo + (size_t)b * 65536 + g * 8;

        f32x4 C[3][4];
        #pragma unroll
        for (int m = 0; m < 3; ++m)
            #pragma unroll
            for (int t = 0; t < 4; ++t) C[m][t] = (f32x4){0.f, 0.f, 0.f, 0.f};

        #pragma unroll
        for (int kk = 0; kk < 4; ++kk) {
            bf16x8 bH[4], bL[4];
            #pragma unroll
            for (int t = 0; t < 4; ++t) {
                const size_t lo_ = (size_t)(l0 + t * 16 + mR) * DM + kk * 32;
                bH[t] = *(const bf16x8*)(xh + lo_);
                bL[t] = *(const bf16x8*)(xl + lo_);
            }
            #pragma unroll
            for (int m = 0; m < 3; ++m) {
                const bf16x8 aH = *(const bf16x8*)(wAh + m * 2048 + kk * 32);
                const bf16x8 aL = *(const bf16x8*)(wAl + m * 2048 + kk * 32);
                #pragma unroll
                for (int t = 0; t < 4; ++t) {
                    C[m][t] = MFMA(aH, bH[t], C[m][t], 0, 0, 0);
                    C[m][t] = MFMA(aH, bL[t], C[m][t], 0, 0, 0);
                    C[m][t] = MFMA(aL, bH[t], C[m][t], 0, 0, 0);
                }
            }
        }

        // V -> vs[v][l] (plain bf16, padded stride)
        #pragma unroll
        for (int t = 0; t < 4; ++t) {
            const int l = l0 + t * 16 + mR;
            #pragma unroll
            for (int i = 0; i < 4; ++i)
                vs[(4 * g + i) * V_STRIDE + l] =
                    (unsigned short)(bfr(C[2][t][i]) >> 16);
        }
        // Q/K -> split rows [hi(16)|lo(16)], padded stride; K pre-scaled
        #pragma unroll
        for (int m = 0; m < 2; ++m) {
            const float scale = m ? (0.25f * 1.44269504f) : 1.0f;
            unsigned short* __restrict__ dst = m ? ks : qs;
            #pragma unroll
            for (int t = 0; t < 4; ++t) {
                const int l = l0 + t * 16 + mR;
                ushort4 hi4, lo4;
                #pragma unroll
                for (int i = 0; i < 4; ++i) {
                    const float v = C[m][t][i] * scale;
                    const unsigned h = bfr(v);
                    const unsigned lw = bfr(v - __uint_as_float(h));
                    ((unsigned short*)&hi4)[i] = (unsigned short)(h >> 16);
                    ((unsigned short*)&lo4)[i] = (unsigned short)(lw >> 16);
                }
                *(ushort4*)(dst + l * QK_STRIDE + 4 * g)      = hi4;
                *(ushort4*)(dst + l * QK_STRIDE + 16 + 4 * g) = lo4;
            }
        }
    }

    __syncthreads();

    // ---------------- Phase 2: flash attention from LDS ----------------
    bf16x8 K0[2], K0s[2], K1[2], K1s[2];
    #pragma unroll
    for (int sub = 0; sub < 2; ++sub) {
        const unsigned short* Kr0 = ks + (wv * 64 + sub * 32 + mR) * QK_STRIDE;
        const unsigned short* Kr1 = Kr0 + 16 * QK_STRIDE;
        K0[sub]  = *(const bf16x8*)(Kr0 + g * 8);
        K0s[sub] = *(const bf16x8*)(Kr0 + (g ^ 2) * 8);
        K1[sub]  = *(const bf16x8*)(Kr1 + g * 8);
        K1s[sub] = *(const bf16x8*)(Kr1 + (g ^ 2) * 8);
    }

    const unsigned short* qrow = qs + mR * QK_STRIDE + g * 8;
    const unsigned short* vrow = vs + mR * V_STRIDE + g * 8;

    f32x4 O[2][2];
    float bar[2][2], sm[2][2];
    #pragma unroll
    for (int sub = 0; sub < 2; ++sub)
        #pragma unroll
        for (int gr = 0; gr < 2; ++gr) {
            O[sub][gr]   = (f32x4){0.f, 0.f, 0.f, 0.f};
            bar[sub][gr] = -1e30f;
            sm[sub][gr]  = 0.f;
        }

    const int aLo = ((g & 1) * 32 + mR) * 4;
    const int aHi = aLo + 64;
    const bool up = (g < 2);

    for (int l = 0; l < LL; l += 32) {
        const bf16x8 aQ0 = *(const bf16x8*)(qrow + l * QK_STRIDE);
        const bf16x8 aQ1 = *(const bf16x8*)(qrow + (l + 16) * QK_STRIDE);
        const bf16x8 aV  = *(const bf16x8*)(vrow + l);

        #pragma unroll
        for (int sub = 0; sub < 2; ++sub) {
            const f32x4 z = {0.f,0.f,0.f,0.f};
            f32x4 sA0 = MFMA(aQ0, K0[sub], z, 0,0,0);
            sA0 = MFMA(aQ0, K0s[sub], sA0, 0,0,0);
            f32x4 sB0 = MFMA(aQ0, K1[sub], z, 0,0,0);
            sB0 = MFMA(aQ0, K1s[sub], sB0, 0,0,0);
            f32x4 sA1 = MFMA(aQ1, K0[sub], z, 0,0,0);
            sA1 = MFMA(aQ1, K0s[sub], sA1, 0,0,0);
            f32x4 sB1 = MFMA(aQ1, K1[sub], z, 0,0,0);
            sB1 = MFMA(aQ1, K1s[sub], sB1, 0,0,0);

            float tmA = fmaxf(fmaxf(fmaxf(sA0[0],sA0[1]), fmaxf(sA0[2],sA0[3])),
                              fmaxf(fmaxf(sA1[0],sA1[1]), fmaxf(sA1[2],sA1[3])));
            float tmB = fmaxf(fmaxf(fmaxf(sB0[0],sB0[1]), fmaxf(sB0[2],sB0[3])),
                              fmaxf(fmaxf(sB1[0],sB1[1]), fmaxf(sB1[2],sB1[3])));
            tmA = fmaxf(tmA, __shfl_xor(tmA, 16, 64));
            tmA = fmaxf(tmA, __shfl_xor(tmA, 32, 64));
            tmB = fmaxf(tmB, __shfl_xor(tmB, 16, 64));
            tmB = fmaxf(tmB, __shfl_xor(tmB, 32, 64));

            const bool pA = __any(tmA + 64.f > bar[sub][0]);
            const bool pB = __any(tmB + 64.f > bar[sub][1]);
            if (pA) soft_pv(sA0, sA1, tmA, bar[sub][0], sm[sub][0],
                            O[sub][0], aV, aLo, aHi, up);
            if (pB) soft_pv(sB0, sB1, tmB, bar[sub][1], sm[sub][1],
                            O[sub][1], aV, aLo, aHi, up);
        }
    }

    const int h = hb / NB, bb = hb % NB;
    #pragma unroll
    for (int sub = 0; sub < 2; ++sub) {
        float s0 = sm[sub][0], s1 = sm[sub][1];
        s0 += __shfl_xor(s0, 16, 64);  s0 += __shfl_xor(s0, 32, 64);
        s1 += __shfl_xor(s1, 16, 64);  s1 += __shfl_xor(s1, 32, 64);
        const float i0 = 1.f / s0, i1 = 1.f / s1;

        unsigned short* __restrict__ ho =
            ht + (size_t)bb * 65536 +
            (size_t)(wv * 64 + sub * 32 + mR) * DM + h * 16 + 4 * g;
        ushort4 p0, p1;
        #pragma unroll
        for (int i = 0; i < 4; ++i) {
            ((unsigned short*)&p0)[i] =
                (unsigned short)(bfr(O[sub][0][i] * i0) >> 16);
            ((unsigned short*)&p1)[i] =
                (unsigned short)(bfr(O[sub][1][i] * i1) >> 16);
        }
        *(ushort4*)ho             = p0;
        *(ushort4*)(ho + 16 * DM) = p1;
    }
}

// ---------------------------------------------------------------------------
// Kernel 3: out = Wo @ headT on MFMA. 768 blocks = (b, mq 2, nq 16) x 4 waves.
// Wo is read as fp32 and converted to bf16 A-frags in-kernel (4 cvt_pk per
// k-step) -- drops the prep Wo branch and its bf16 buffer.
// ---------------------------------------------------------------------------
__global__ __launch_bounds__(256)
void out_mfma(const float* __restrict__ Wo,
              const unsigned short* __restrict__ ht,
              float* __restrict__ out)
{
    const int blk  = blockIdx.x;
    const int b    = blk >> 5;
    const int mq   = (blk >> 4) & 1;
    const int nq   = blk & 15;
    const int wv   = threadIdx.x >> 6;
    const int lane = threadIdx.x & 63;
    const int g = lane >> 4, mR = lane & 15;
    const int m0 = (mq * 4 + wv) * 16;
    const int n0 = nq * 32;

    const float* __restrict__ A =
        Wo + (size_t)b * 16384 + (size_t)(m0 + mR) * DM + g * 8;
    const unsigned short* __restrict__ B = ht + (size_t)b * 65536 + g * 8;

    f32x4 C0 = {0.f,0.f,0.f,0.f}, C1 = {0.f,0.f,0.f,0.f};
    #pragma unroll
    for (int kk = 0; kk < 4; ++kk) {
        const float4 f0 = *(const float4*)(A + kk * 32);
        const float4 f1 = *(const float4*)(A + kk * 32 + 4);
        i32x4 w;
        w[0] = (int)cvtpk(f0.x, f0.y);
        w[1] = (int)cvtpk(f0.z, f0.w);
        w[2] = (int)cvtpk(f1.x, f1.y);
        w[3] = (int)cvtpk(f1.z, f1.w);
        const bf16x8 aW = __builtin_bit_cast(bf16x8, w);
        const bf16x8 b0 = *(const bf16x8*)(B + (size_t)(n0 + mR) * DM + kk * 32);
        const bf16x8 b1 = *(const bf16x8*)(B + (size_t)(n0 + 16 + mR) * DM + kk * 32);
        C0 = MFMA(aW, b0, C0, 0, 0, 0);
        C1 = MFMA(aW, b1, C1, 0, 0, 0);
    }

    float* __restrict__ ob = out + (size_t)b * 65536 + (size_t)(m0 + 4 * g) * LL;
    #pragma unroll
    for (int i = 0; i < 4; ++i) {
        ob[(size_t)i * LL + n0 + mR]      = C0[i];
        ob[(size_t)i * LL + n0 + 16 + mR] = C1[i];
    }
}

extern "C" void kernel_launch(void* const* d_in, const int* in_sizes, int n_in,
                              void* d_out, int out_size, void* d_ws, size_t ws_size,
                              hipStream_t stream) {
    const float* x  = (const float*)d_in[0];
    const float* Wq = (const float*)d_in[1];
    const float* Wk = (const float*)d_in[2];
    const float* Wv = (const float*)d_in[3];
    const float* Wo = (const float*)d_in[4];
    float* out = (float*)d_out;

    char* ws = (char*)d_ws;
    unsigned short* xthi = (unsigned short*)(ws + XTH_OFF);
    unsigned short* xtlo = (unsigned short*)(ws + XTL_OFF);
    unsigned short* whi  = (unsigned short*)(ws + WHI_OFF);
    unsigned short* wlo  = (unsigned short*)(ws + WLO_OFF);
    unsigned short* ht   = (unsigned short*)(ws + HT_OFF);

    prep     <<<768,     256, 0, stream>>>(x, Wq, Wk, Wv, xthi, xtlo, whi, wlo);
    qkv_attn <<<HB,      512, 0, stream>>>(xthi, xtlo, whi, wlo, ht);
    out_mfma <<<NB * 32, 256, 0, stream>>>(Wo, ht, out);
}